// Round 11
// baseline (90.971 us; speedup 1.0000x reference)
//
#include <hip/hip_runtime.h>

// SSIM v23: v20 structure (BY=256, block-cooperative coalesced staging,
// double-buffered LDS ring, raw s_barrier + lgkm-only drain) with the
// load pipeline DEEPENED to 2 chunks ahead via a 3-slot register ring.
// Evidence R8/R10: delivered BW tracks per-wave outstanding bytes, not
// block count (v22: 2x grid -> +4% BW; v21: spill traffic alone pushed
// chip to 3.25 TB/s). v20/v22 kept only 3 f4 in flight and drained them
// at every WRC (vmcnt wait targeted 1-step-old loads). v23: LOADC(c+3)
// at step c, WRC(c+1) consumes 2-step-old loads -> counted vmcnt(6) with
// 2 compute-steps of cover (no stall), 6 f4 = 96B sustained in flight.
// Schedule period lcm(3 slots, 2 bufs) = 6: rolled 2x loop of 6 static-
// name steps + explicit tail (v20-proven SROA-safe pattern).
// Math byte-identical to v20/v22 (absmax must stay exactly 0.0078125).

typedef __attribute__((ext_vector_type(8))) short bf16x8;
typedef __attribute__((ext_vector_type(4))) float f32x4;

constexpr int TX   = 64;             // block out-cols (4 waves x 16)
constexpr int BY   = 256;            // block out-rows
constexpr int IMW  = 512;
constexpr int IMH  = 512;
constexpr int NPL  = 48;
constexpr int GX   = IMW / TX;       // 8
constexpr int GYB  = IMH / BY;       // 2
constexpr int NBLK = GX * GYB * NPL; // 768
constexpr int NCH  = BY / 16;        // 16; chunks 0..16
constexpr int CB   = 12288;          // bytes per chunk buffer (768 float4)
constexpr float C1c = 0.01f * 0.01f;
constexpr float C2c = 0.03f * 0.03f;

union frag {
    bf16x8 f;
    unsigned int u[4];
    uint4 q;
};

// RNE f32->bf16 pair pack (setup kernel only).
__device__ __forceinline__ unsigned int pk_bf16(float lo, float hi) {
    unsigned int a = __float_as_uint(lo);
    unsigned int b = __float_as_uint(hi);
    a += 0x7FFFu + ((a >> 16) & 1u);
    b += 0x7FFFu + ((b >> 16) & 1u);
    return (b & 0xFFFF0000u) | (a >> 16);
}

// Fast pack: round-half-up + byte-perm merge (3 VALU ops per pair).
__device__ __forceinline__ unsigned int pk_rhu(float lo, float hi, unsigned sel) {
    unsigned int a = __float_as_uint(lo) + 0x8000u;
    unsigned int b = __float_as_uint(hi) + 0x8000u;
    unsigned int r;
    asm("v_perm_b32 %0, %1, %2, %3" : "=v"(r) : "v"(b), "v"(a), "s"(sel));
    return r;
}

// Normalized 11-tap Gaussian (sigma=1.5); wt[d] for d in [0,11), else 0.
__device__ __forceinline__ float wsel(int d) {
    float w = 0.f;
    w = (d == 0 || d == 10) ? 0.00102838f : w;
    w = (d == 1 || d == 9)  ? 0.00759876f : w;
    w = (d == 2 || d == 8)  ? 0.03600077f : w;
    w = (d == 3 || d == 7)  ? 0.10936082f : w;
    w = (d == 4 || d == 6)  ? 0.21300553f : w;
    w = (d == 5)            ? 0.26601171f : w;
    return w;
}

// Per-lane weight fragments (8 words/lane):
//   words 0..3: whf  — H-pass B-frag,  W[k][n] = wt[k-n-3],   k = lg*8+j
//   words 4..7: whv  — V-pass A-frag with permuted rows,
//                      W'[k][n] = wt[wr(k)-n-3],
//                      wr(k) = (j<4 ? lg*4+j : 12+lg*4+j), j = k&7
__global__ void ssim_weight_setup(unsigned int* __restrict__ wbuf)
{
    const int lane = threadIdx.x & 63;
    const int ln   = lane & 15;
    const int lg   = lane >> 4;
#pragma unroll
    for (int w = 0; w < 4; ++w) {
        const int ka = lg * 8 + 2 * w;
        wbuf[lane * 8 + w] = pk_bf16(wsel(ka - ln - 3), wsel(ka + 1 - ln - 3));
        const int j0  = 2 * w;
        const int wr0 = (j0 < 4) ? (lg * 4 + j0) : (12 + lg * 4 + j0);
        wbuf[lane * 8 + 4 + w] = pk_bf16(wsel(wr0 - ln - 3), wsel(wr0 + 1 - ln - 3));
    }
}

// Clamped coalesced float4 load (OOB rows/cols fetch valid garbage that is
// zeroed at the fragment stage -- never fed into the math).
__device__ __forceinline__ float4 ldf4(const float* __restrict__ gb, int ir, int colc)
{
    ir = ir < 0 ? 0 : (ir > IMH - 1 ? IMH - 1 : ir);
    return *reinterpret_cast<const float4*>(gb + (size_t)ir * IMW + colc);
}

// H-pass for one chunk from LDS: read 2 f4/img (= v12's 8 fragment floats),
// zero-predicate, pack, 5 MFMAs -> packed D (uint2 per plane).
template<int OFF>
__device__ __forceinline__ void cstep(const char* lds, int ro0, int ro1, bool ok,
                                      const frag& whf, unsigned sel,
                                      uint2* __restrict__ D)
{
    float4 ra0 = *reinterpret_cast<const float4*>(lds + OFF + ro0);
    float4 ra1 = *reinterpret_cast<const float4*>(lds + OFF + ro1);
    float4 rb0 = *reinterpret_cast<const float4*>(lds + OFF + CB / 2 + ro0);
    float4 rb1 = *reinterpret_cast<const float4*>(lds + OFF + CB / 2 + ro1);
    const float4 zz = make_float4(0.f, 0.f, 0.f, 0.f);
    if (!ok) { ra0 = zz; ra1 = zz; rb0 = zz; rb1 = zz; }

    const f32x4 z = {0.f, 0.f, 0.f, 0.f};
    frag fa, fb, faa, fbb, fab;
    fa.u[0]  = pk_rhu(ra0.x, ra0.y, sel);          fb.u[0]  = pk_rhu(rb0.x, rb0.y, sel);
    faa.u[0] = pk_rhu(ra0.x*ra0.x, ra0.y*ra0.y, sel);
    fbb.u[0] = pk_rhu(rb0.x*rb0.x, rb0.y*rb0.y, sel);
    fab.u[0] = pk_rhu(ra0.x*rb0.x, ra0.y*rb0.y, sel);
    fa.u[1]  = pk_rhu(ra0.z, ra0.w, sel);          fb.u[1]  = pk_rhu(rb0.z, rb0.w, sel);
    faa.u[1] = pk_rhu(ra0.z*ra0.z, ra0.w*ra0.w, sel);
    fbb.u[1] = pk_rhu(rb0.z*rb0.z, rb0.w*rb0.w, sel);
    fab.u[1] = pk_rhu(ra0.z*rb0.z, ra0.w*rb0.w, sel);
    fa.u[2]  = pk_rhu(ra1.x, ra1.y, sel);          fb.u[2]  = pk_rhu(rb1.x, rb1.y, sel);
    faa.u[2] = pk_rhu(ra1.x*ra1.x, ra1.y*ra1.y, sel);
    fbb.u[2] = pk_rhu(rb1.x*rb1.x, rb1.y*rb1.y, sel);
    fab.u[2] = pk_rhu(ra1.x*rb1.x, ra1.y*rb1.y, sel);
    fa.u[3]  = pk_rhu(ra1.z, ra1.w, sel);          fb.u[3]  = pk_rhu(rb1.z, rb1.w, sel);
    faa.u[3] = pk_rhu(ra1.z*ra1.z, ra1.w*ra1.w, sel);
    fbb.u[3] = pk_rhu(rb1.z*rb1.z, rb1.w*rb1.w, sel);
    fab.u[3] = pk_rhu(ra1.z*rb1.z, ra1.w*rb1.w, sel);

    f32x4 d;
    d = __builtin_amdgcn_mfma_f32_16x16x32_bf16(fa.f,  whf.f, z, 0, 0, 0);
    D[0] = make_uint2(pk_rhu(d[0], d[1], sel), pk_rhu(d[2], d[3], sel));
    d = __builtin_amdgcn_mfma_f32_16x16x32_bf16(fb.f,  whf.f, z, 0, 0, 0);
    D[1] = make_uint2(pk_rhu(d[0], d[1], sel), pk_rhu(d[2], d[3], sel));
    d = __builtin_amdgcn_mfma_f32_16x16x32_bf16(faa.f, whf.f, z, 0, 0, 0);
    D[2] = make_uint2(pk_rhu(d[0], d[1], sel), pk_rhu(d[2], d[3], sel));
    d = __builtin_amdgcn_mfma_f32_16x16x32_bf16(fbb.f, whf.f, z, 0, 0, 0);
    D[3] = make_uint2(pk_rhu(d[0], d[1], sel), pk_rhu(d[2], d[3], sel));
    d = __builtin_amdgcn_mfma_f32_16x16x32_bf16(fab.f, whf.f, z, 0, 0, 0);
    D[4] = make_uint2(pk_rhu(d[0], d[1], sel), pk_rhu(d[2], d[3], sel));
}

// V-pass for one 16-row out-tile from D_prev (chunk t) + D_cur (chunk t+1).
__device__ __forceinline__ void vstep(const frag& whv,
                                      const uint2* __restrict__ Dp,
                                      const uint2* __restrict__ Dc,
                                      float& lsum)
{
    const f32x4 z = {0.f, 0.f, 0.f, 0.f};
    f32x4 res[5];
#pragma unroll
    for (int p = 0; p < 5; ++p) {
        frag Bf;
        Bf.u[0] = Dp[p].x; Bf.u[1] = Dp[p].y;
        Bf.u[2] = Dc[p].x; Bf.u[3] = Dc[p].y;
        res[p] = __builtin_amdgcn_mfma_f32_16x16x32_bf16(whv.f, Bf.f, z, 0, 0, 0);
    }
#pragma unroll
    for (int j = 0; j < 4; ++j) {
        const float mu1 = res[0][j];
        const float mu2 = res[1][j];
        const float m1s = mu1 * mu1;
        const float m2s = mu2 * mu2;
        const float m12 = mu1 * mu2;
        const float s11 = res[2][j] - m1s;
        const float s22 = res[3][j] - m2s;
        const float s12 = res[4][j] - m12;
        const float num = (2.f * m12 + C1c) * (2.f * s12 + C2c);
        const float den = (m1s + m2s + C1c) * (s11 + s22 + C2c);
        lsum = fmaf(num, __builtin_amdgcn_rcpf(den), lsum);
    }
}

__global__ __launch_bounds__(256, 4)
void ssim_mfma(const float* __restrict__ img1, const float* __restrict__ img2,
               const unsigned int* __restrict__ wbuf,
               float* __restrict__ partials)
{
    const int tid  = threadIdx.x;
    const int lane = tid & 63;
    const int wave = tid >> 6;        // 0..3
    const int ln   = lane & 15;
    const int lg   = lane >> 4;       // 0..3
    const int bx   = blockIdx.x;
    const int y0   = blockIdx.y * BY;
    const float* __restrict__ p1 = img1 + (size_t)blockIdx.z * (IMW * IMH);
    const float* __restrict__ p2 = img2 + (size_t)blockIdx.z * (IMW * IMH);
    const unsigned int sel = 0x07060302u;

    frag whf, whv;
    whf.q = reinterpret_cast<const uint4*>(wbuf)[lane * 2];
    whv.q = reinterpret_cast<const uint4*>(wbuf)[lane * 2 + 1];

    __shared__ __align__(16) char lds[2 * CB];
    __shared__ float wsum[4];

    // ---- per-thread load-slot constants (3 slots: L = tid, tid+256, tid+512)
    // within-img index Lp = L%384; row = Lp/24; slot k = Lp%24 holds global
    // seg (k-row)%24 of window col = bx*64-16+4*seg (rotate swizzle).
    const int Lp0 = tid;                       // L0 < 384 -> img1
    const int rw0 = Lp0 / 24;
    int sg0 = (Lp0 % 24) - rw0; sg0 += (sg0 < 0) ? 24 : 0;
    int cc0 = bx * TX - 16 + 4 * sg0; cc0 = cc0 < 0 ? 0 : (cc0 > IMW - 4 ? IMW - 4 : cc0);
    const float* gb0 = p1;
    const int wo0 = tid * 16;

    const int L1  = tid + 256;
    const int Lp1 = (L1 < 384) ? L1 : (L1 - 384);
    const int rw1 = Lp1 / 24;
    int sg1 = (Lp1 % 24) - rw1; sg1 += (sg1 < 0) ? 24 : 0;
    int cc1 = bx * TX - 16 + 4 * sg1; cc1 = cc1 < 0 ? 0 : (cc1 > IMW - 4 ? IMW - 4 : cc1);
    const float* gb1 = (L1 < 384) ? p1 : p2;
    const int wo1 = L1 * 16;

    const int L2  = tid + 512;                 // >= 512 -> img2
    const int Lp2 = L2 - 384;
    const int rw2 = Lp2 / 24;
    int sg2 = (Lp2 % 24) - rw2; sg2 += (sg2 < 0) ? 24 : 0;
    int cc2 = bx * TX - 16 + 4 * sg2; cc2 = cc2 < 0 ? 0 : (cc2 > IMW - 4 ? IMW - 4 : cc2);
    const float* gb2 = p2;
    const int wo2 = L2 * 16;

    // ---- fragment read offsets (loop-invariant): row ln, segs s0, s0+1
    const int s0  = 4 * wave + 2 + 2 * lg;
    const int rk0 = (s0 + ln) % 24;
    const int rk1 = (s0 + 1 + ln) % 24;
    const int ro0 = (ln * 24 + rk0) * 16;
    const int ro1 = (ln * 24 + rk1) * 16;
    const int cbase = bx * TX + wave * 16 - 8 + lg * 8;
    const bool colok = ((unsigned)cbase <= (unsigned)(IMW - 8));

    // 3-slot staging ring: slot holds chunk c with c%3 == {0:A, 1:B, 2:C}
    float4 sA0, sA1, sA2, sB0, sB1, sB2, sC0, sC1, sC2;
    uint2 DA[5], DB[5];
    float lsum = 0.f;

#define LOADC(c, X0, X1, X2) do{ \
    X0 = ldf4(gb0, y0 + 16 * (c) - 8 + rw0, cc0); \
    X1 = ldf4(gb1, y0 + 16 * (c) - 8 + rw1, cc1); \
    X2 = ldf4(gb2, y0 + 16 * (c) - 8 + rw2, cc2); } while (0)
#define WRC(OFF, X0, X1, X2) do{ \
    *reinterpret_cast<float4*>(lds + (OFF) + wo0) = X0; \
    *reinterpret_cast<float4*>(lds + (OFF) + wo1) = X1; \
    *reinterpret_cast<float4*>(lds + (OFF) + wo2) = X2; } while (0)
#define BAR() do{ \
    asm volatile("s_waitcnt lgkmcnt(0)" ::: "memory"); \
    __builtin_amdgcn_sched_barrier(0); \
    __builtin_amdgcn_s_barrier(); \
    __builtin_amdgcn_sched_barrier(0); } while (0)
#define ROWOK(c) (colok && ((unsigned)(y0 + 16 * (c) - 8 + ln) < (unsigned)IMH))

    // ---- prologue: chunks 0..3 issued; buf0=chunk0, buf1=chunk1;
    // chunks 2,3 stay in flight in regs (2-chunk cover established).
    LOADC(0, sA0, sA1, sA2);
    LOADC(1, sB0, sB1, sB2);
    LOADC(2, sC0, sC1, sC2);
    WRC(0, sA0, sA1, sA2);                 // waits chunk0 only (vmcnt counted)
    BAR();                                 // buf0 ready
    LOADC(3, sA0, sA1, sA2);
    WRC(CB, sB0, sB1, sB2);                // waits chunk1; 2,3 in flight
    cstep<0>(lds, ro0, ro1, ROWOK(0), whf, sel, DA);   // H of chunk 0
    BAR();                                 // buf1 ready

    // ---- main march: steps c=1..12 as 2 x 6-step period (slot ring x bufs),
    // then explicit tail c=13..16. At step c: LOADC(c+3), WRC(chunk c+1,
    // loaded 2 steps ago -> vmcnt wait has 2 compute-steps of cover),
    // cstep(chunk c), vstep(tile c-1), BAR.
    for (int u = 0; u < 2; ++u) {
        const int c0 = 6 * u;
        // c = c0+1 (odd: cstep buf1)
        LOADC(c0 + 4, sB0, sB1, sB2);
        WRC(0, sC0, sC1, sC2);             // chunk c0+2 -> buf0
        cstep<CB>(lds, ro0, ro1, ROWOK(c0 + 1), whf, sel, DB);
        vstep(whv, DA, DB, lsum);
        BAR();
        // c = c0+2
        LOADC(c0 + 5, sC0, sC1, sC2);
        WRC(CB, sA0, sA1, sA2);            // chunk c0+3 -> buf1
        cstep<0>(lds, ro0, ro1, ROWOK(c0 + 2), whf, sel, DA);
        vstep(whv, DB, DA, lsum);
        BAR();
        // c = c0+3
        LOADC(c0 + 6, sA0, sA1, sA2);
        WRC(0, sB0, sB1, sB2);             // chunk c0+4 -> buf0
        cstep<CB>(lds, ro0, ro1, ROWOK(c0 + 3), whf, sel, DB);
        vstep(whv, DA, DB, lsum);
        BAR();
        // c = c0+4
        LOADC(c0 + 7, sB0, sB1, sB2);
        WRC(CB, sC0, sC1, sC2);            // chunk c0+5 -> buf1
        cstep<0>(lds, ro0, ro1, ROWOK(c0 + 4), whf, sel, DA);
        vstep(whv, DB, DA, lsum);
        BAR();
        // c = c0+5
        LOADC(c0 + 8, sC0, sC1, sC2);
        WRC(0, sA0, sA1, sA2);             // chunk c0+6 -> buf0
        cstep<CB>(lds, ro0, ro1, ROWOK(c0 + 5), whf, sel, DB);
        vstep(whv, DA, DB, lsum);
        BAR();
        // c = c0+6
        LOADC(c0 + 9, sA0, sA1, sA2);
        WRC(CB, sB0, sB1, sB2);            // chunk c0+7 -> buf1
        cstep<0>(lds, ro0, ro1, ROWOK(c0 + 6), whf, sel, DA);
        vstep(whv, DB, DA, lsum);
        BAR();
    }
    // c = 13
    LOADC(16, sB0, sB1, sB2);
    WRC(0, sC0, sC1, sC2);                 // chunk 14 -> buf0
    cstep<CB>(lds, ro0, ro1, ROWOK(13), whf, sel, DB);
    vstep(whv, DA, DB, lsum);
    BAR();
    // c = 14
    WRC(CB, sA0, sA1, sA2);                // chunk 15 -> buf1
    cstep<0>(lds, ro0, ro1, ROWOK(14), whf, sel, DA);
    vstep(whv, DB, DA, lsum);
    BAR();
    // c = 15
    WRC(0, sB0, sB1, sB2);                 // chunk 16 -> buf0
    cstep<CB>(lds, ro0, ro1, ROWOK(15), whf, sel, DB);
    vstep(whv, DA, DB, lsum);
    BAR();
    // c = 16
    cstep<0>(lds, ro0, ro1, ROWOK(16), whf, sel, DA);
    vstep(whv, DB, DA, lsum);
#undef LOADC
#undef WRC
#undef BAR
#undef ROWOK

    // ---- Block reduction -> per-block partial ----
#pragma unroll
    for (int off = 32; off > 0; off >>= 1)
        lsum += __shfl_down(lsum, off, 64);

    if (lane == 0) wsum[wave] = lsum;
    __syncthreads();
    if (tid == 0) {
        float tot = wsum[0] + wsum[1] + wsum[2] + wsum[3];
        const int bid = (blockIdx.z * gridDim.y + blockIdx.y) * gridDim.x + blockIdx.x;
        partials[bid] = tot;
    }
}

__global__ __launch_bounds__(256)
void ssim_reduce_kernel(const float* __restrict__ partials,
                        float* __restrict__ out)
{
    __shared__ double sm[256];
    double s = 0.0;
    for (int i = threadIdx.x; i < NBLK; i += 256) s += (double)partials[i];
    sm[threadIdx.x] = s;
    __syncthreads();
    for (int stride = 128; stride > 0; stride >>= 1) {
        if (threadIdx.x < stride) sm[threadIdx.x] += sm[threadIdx.x + stride];
        __syncthreads();
    }
    if (threadIdx.x == 0) {
        double mean = sm[0] / (double)((size_t)NPL * IMW * IMH);
        out[0] = (float)(1.0 - mean);
    }
}

extern "C" void kernel_launch(void* const* d_in, const int* in_sizes, int n_in,
                              void* d_out, int out_size, void* d_ws, size_t ws_size,
                              hipStream_t stream)
{
    (void)in_sizes; (void)n_in; (void)out_size; (void)ws_size;
    const float* img1 = (const float*)d_in[0];
    const float* img2 = (const float*)d_in[1];
    float* out = (float*)d_out;

    unsigned int* wbuf = (unsigned int*)d_ws;              // 2 KB weight table
    float* partials = (float*)((char*)d_ws + 4096);        // NBLK floats

    ssim_weight_setup<<<1, 64, 0, stream>>>(wbuf);
    dim3 grid(GX, GYB, NPL);
    ssim_mfma<<<grid, 256, 0, stream>>>(img1, img2, wbuf, partials);
    ssim_reduce_kernel<<<1, 256, 0, stream>>>(partials, out);
}

// Round 12
// 43.496 us; speedup vs baseline: 2.0915x; 2.0915x over previous
//
#include <hip/hip_runtime.h>

// SSIM v24: v20 structure (BY=256, coalesced block staging, double-... now
// QUAD-buffered LDS) with staging moved to __builtin_amdgcn_global_load_lds.
// R9/R11: any register-staged prefetch deeper than 2 slots gets demoted to
// scratch by the backend's occupancy heuristic (4 failures: v16/17/19/21/23).
// gload_lds removes registers from the staging path entirely: dest is
// wave-uniform base + lane*16 (our layout tid*16 is exactly that); the
// rotate swizzle is baked into the per-lane SOURCE address (m173 pattern);
// bytes land in identical LDS slots -> bit-identical math (absmax must
// stay exactly 0.0078125).
// Pipeline (T3/T4): 4 bufs x 12KB, depth-2: step c ISSUEs chunk c+2 into
// buf[(c+2)%4] (last read at step c-2, race-free with ONE barrier/step),
// then s_waitcnt vmcnt(6) -> chunk c's writes complete, chunks c+1/c+2
// stay in flight ACROSS the barrier (never drain to 0 mid-loop).
// Tail: c=15 vmcnt(3), c=16 vmcnt(0). In-flight 96B/thread sustained.

typedef __attribute__((ext_vector_type(8))) short bf16x8;
typedef __attribute__((ext_vector_type(4))) float f32x4;

constexpr int TX   = 64;             // block out-cols (4 waves x 16)
constexpr int BY   = 256;            // block out-rows
constexpr int IMW  = 512;
constexpr int IMH  = 512;
constexpr int NPL  = 48;
constexpr int GX   = IMW / TX;       // 8
constexpr int GYB  = IMH / BY;       // 2
constexpr int NBLK = GX * GYB * NPL; // 768
constexpr int NCH  = BY / 16;        // 16; chunks 0..16
constexpr int CB   = 12288;          // bytes per chunk buffer (768 float4)
constexpr float C1c = 0.01f * 0.01f;
constexpr float C2c = 0.03f * 0.03f;

union frag {
    bf16x8 f;
    unsigned int u[4];
    uint4 q;
};

// RNE f32->bf16 pair pack (setup kernel only).
__device__ __forceinline__ unsigned int pk_bf16(float lo, float hi) {
    unsigned int a = __float_as_uint(lo);
    unsigned int b = __float_as_uint(hi);
    a += 0x7FFFu + ((a >> 16) & 1u);
    b += 0x7FFFu + ((b >> 16) & 1u);
    return (b & 0xFFFF0000u) | (a >> 16);
}

// Fast pack: round-half-up + byte-perm merge (3 VALU ops per pair).
__device__ __forceinline__ unsigned int pk_rhu(float lo, float hi, unsigned sel) {
    unsigned int a = __float_as_uint(lo) + 0x8000u;
    unsigned int b = __float_as_uint(hi) + 0x8000u;
    unsigned int r;
    asm("v_perm_b32 %0, %1, %2, %3" : "=v"(r) : "v"(b), "v"(a), "s"(sel));
    return r;
}

// Normalized 11-tap Gaussian (sigma=1.5); wt[d] for d in [0,11), else 0.
__device__ __forceinline__ float wsel(int d) {
    float w = 0.f;
    w = (d == 0 || d == 10) ? 0.00102838f : w;
    w = (d == 1 || d == 9)  ? 0.00759876f : w;
    w = (d == 2 || d == 8)  ? 0.03600077f : w;
    w = (d == 3 || d == 7)  ? 0.10936082f : w;
    w = (d == 4 || d == 6)  ? 0.21300553f : w;
    w = (d == 5)            ? 0.26601171f : w;
    return w;
}

// Per-lane weight fragments (8 words/lane):
//   words 0..3: whf  — H-pass B-frag,  W[k][n] = wt[k-n-3],   k = lg*8+j
//   words 4..7: whv  — V-pass A-frag with permuted rows,
//                      W'[k][n] = wt[wr(k)-n-3],
//                      wr(k) = (j<4 ? lg*4+j : 12+lg*4+j), j = k&7
__global__ void ssim_weight_setup(unsigned int* __restrict__ wbuf)
{
    const int lane = threadIdx.x & 63;
    const int ln   = lane & 15;
    const int lg   = lane >> 4;
#pragma unroll
    for (int w = 0; w < 4; ++w) {
        const int ka = lg * 8 + 2 * w;
        wbuf[lane * 8 + w] = pk_bf16(wsel(ka - ln - 3), wsel(ka + 1 - ln - 3));
        const int j0  = 2 * w;
        const int wr0 = (j0 < 4) ? (lg * 4 + j0) : (12 + lg * 4 + j0);
        wbuf[lane * 8 + 4 + w] = pk_bf16(wsel(wr0 - ln - 3), wsel(wr0 + 1 - ln - 3));
    }
}

// H-pass for one chunk from LDS: read 2 f4/img (= v12's 8 fragment floats),
// zero-predicate, pack, 5 MFMAs -> packed D (uint2 per plane).
template<int OFF>
__device__ __forceinline__ void cstep(const char* lds, int ro0, int ro1, bool ok,
                                      const frag& whf, unsigned sel,
                                      uint2* __restrict__ D)
{
    float4 ra0 = *reinterpret_cast<const float4*>(lds + OFF + ro0);
    float4 ra1 = *reinterpret_cast<const float4*>(lds + OFF + ro1);
    float4 rb0 = *reinterpret_cast<const float4*>(lds + OFF + CB / 2 + ro0);
    float4 rb1 = *reinterpret_cast<const float4*>(lds + OFF + CB / 2 + ro1);
    const float4 zz = make_float4(0.f, 0.f, 0.f, 0.f);
    if (!ok) { ra0 = zz; ra1 = zz; rb0 = zz; rb1 = zz; }

    const f32x4 z = {0.f, 0.f, 0.f, 0.f};
    frag fa, fb, faa, fbb, fab;
    fa.u[0]  = pk_rhu(ra0.x, ra0.y, sel);          fb.u[0]  = pk_rhu(rb0.x, rb0.y, sel);
    faa.u[0] = pk_rhu(ra0.x*ra0.x, ra0.y*ra0.y, sel);
    fbb.u[0] = pk_rhu(rb0.x*rb0.x, rb0.y*rb0.y, sel);
    fab.u[0] = pk_rhu(ra0.x*rb0.x, ra0.y*rb0.y, sel);
    fa.u[1]  = pk_rhu(ra0.z, ra0.w, sel);          fb.u[1]  = pk_rhu(rb0.z, rb0.w, sel);
    faa.u[1] = pk_rhu(ra0.z*ra0.z, ra0.w*ra0.w, sel);
    fbb.u[1] = pk_rhu(rb0.z*rb0.z, rb0.w*rb0.w, sel);
    fab.u[1] = pk_rhu(ra0.z*rb0.z, ra0.w*rb0.w, sel);
    fa.u[2]  = pk_rhu(ra1.x, ra1.y, sel);          fb.u[2]  = pk_rhu(rb1.x, rb1.y, sel);
    faa.u[2] = pk_rhu(ra1.x*ra1.x, ra1.y*ra1.y, sel);
    fbb.u[2] = pk_rhu(rb1.x*rb1.x, rb1.y*rb1.y, sel);
    fab.u[2] = pk_rhu(ra1.x*rb1.x, ra1.y*rb1.y, sel);
    fa.u[3]  = pk_rhu(ra1.z, ra1.w, sel);          fb.u[3]  = pk_rhu(rb1.z, rb1.w, sel);
    faa.u[3] = pk_rhu(ra1.z*ra1.z, ra1.w*ra1.w, sel);
    fbb.u[3] = pk_rhu(rb1.z*rb1.z, rb1.w*rb1.w, sel);
    fab.u[3] = pk_rhu(ra1.z*rb1.z, ra1.w*rb1.w, sel);

    f32x4 d;
    d = __builtin_amdgcn_mfma_f32_16x16x32_bf16(fa.f,  whf.f, z, 0, 0, 0);
    D[0] = make_uint2(pk_rhu(d[0], d[1], sel), pk_rhu(d[2], d[3], sel));
    d = __builtin_amdgcn_mfma_f32_16x16x32_bf16(fb.f,  whf.f, z, 0, 0, 0);
    D[1] = make_uint2(pk_rhu(d[0], d[1], sel), pk_rhu(d[2], d[3], sel));
    d = __builtin_amdgcn_mfma_f32_16x16x32_bf16(faa.f, whf.f, z, 0, 0, 0);
    D[2] = make_uint2(pk_rhu(d[0], d[1], sel), pk_rhu(d[2], d[3], sel));
    d = __builtin_amdgcn_mfma_f32_16x16x32_bf16(fbb.f, whf.f, z, 0, 0, 0);
    D[3] = make_uint2(pk_rhu(d[0], d[1], sel), pk_rhu(d[2], d[3], sel));
    d = __builtin_amdgcn_mfma_f32_16x16x32_bf16(fab.f, whf.f, z, 0, 0, 0);
    D[4] = make_uint2(pk_rhu(d[0], d[1], sel), pk_rhu(d[2], d[3], sel));
}

// V-pass for one 16-row out-tile from D_prev (chunk t) + D_cur (chunk t+1).
__device__ __forceinline__ void vstep(const frag& whv,
                                      const uint2* __restrict__ Dp,
                                      const uint2* __restrict__ Dc,
                                      float& lsum)
{
    const f32x4 z = {0.f, 0.f, 0.f, 0.f};
    f32x4 res[5];
#pragma unroll
    for (int p = 0; p < 5; ++p) {
        frag Bf;
        Bf.u[0] = Dp[p].x; Bf.u[1] = Dp[p].y;
        Bf.u[2] = Dc[p].x; Bf.u[3] = Dc[p].y;
        res[p] = __builtin_amdgcn_mfma_f32_16x16x32_bf16(whv.f, Bf.f, z, 0, 0, 0);
    }
#pragma unroll
    for (int j = 0; j < 4; ++j) {
        const float mu1 = res[0][j];
        const float mu2 = res[1][j];
        const float m1s = mu1 * mu1;
        const float m2s = mu2 * mu2;
        const float m12 = mu1 * mu2;
        const float s11 = res[2][j] - m1s;
        const float s22 = res[3][j] - m2s;
        const float s12 = res[4][j] - m12;
        const float num = (2.f * m12 + C1c) * (2.f * s12 + C2c);
        const float den = (m1s + m2s + C1c) * (s11 + s22 + C2c);
        lsum = fmaf(num, __builtin_amdgcn_rcpf(den), lsum);
    }
}

__global__ __launch_bounds__(256, 3)
void ssim_mfma(const float* __restrict__ img1, const float* __restrict__ img2,
               const unsigned int* __restrict__ wbuf,
               float* __restrict__ partials)
{
    const int tid  = threadIdx.x;
    const int lane = tid & 63;
    const int wave = tid >> 6;        // 0..3
    const int ln   = lane & 15;
    const int lg   = lane >> 4;       // 0..3
    const int bx   = blockIdx.x;
    const int y0   = blockIdx.y * BY;
    const float* __restrict__ p1 = img1 + (size_t)blockIdx.z * (IMW * IMH);
    const float* __restrict__ p2 = img2 + (size_t)blockIdx.z * (IMW * IMH);
    const unsigned int sel = 0x07060302u;

    frag whf, whv;
    whf.q = reinterpret_cast<const uint4*>(wbuf)[lane * 2];
    whv.q = reinterpret_cast<const uint4*>(wbuf)[lane * 2 + 1];

    __shared__ __align__(16) char lds[4 * CB];     // 4 chunk buffers
    __shared__ float wsum[4];

    // ---- per-thread load-slot constants (3 groups: L = tid, +256, +512).
    // Lp = L%384; row = Lp/24; slot k = Lp%24 holds seg (k-row)%24 of the
    // window [bx*64-16, +80) (rotate swizzle baked into the SOURCE addr;
    // LDS dest is linear L*16 = wave-uniform base + lane*16 per group).
    const int Lp0 = tid;                       // group0 -> img1
    const int rw0 = Lp0 / 24;
    int sg0 = (Lp0 % 24) - rw0; sg0 += (sg0 < 0) ? 24 : 0;
    int cc0 = bx * TX - 16 + 4 * sg0; cc0 = cc0 < 0 ? 0 : (cc0 > IMW - 4 ? IMW - 4 : cc0);
    const float* gb0 = p1;

    const int L1  = tid + 256;
    const int Lp1 = (L1 < 384) ? L1 : (L1 - 384);
    const int rw1 = Lp1 / 24;
    int sg1 = (Lp1 % 24) - rw1; sg1 += (sg1 < 0) ? 24 : 0;
    int cc1 = bx * TX - 16 + 4 * sg1; cc1 = cc1 < 0 ? 0 : (cc1 > IMW - 4 ? IMW - 4 : cc1);
    const float* gb1 = (L1 < 384) ? p1 : p2;

    const int Lp2 = tid + 512 - 384;           // group2 -> img2
    const int rw2 = Lp2 / 24;
    int sg2 = (Lp2 % 24) - rw2; sg2 += (sg2 < 0) ? 24 : 0;
    int cc2 = bx * TX - 16 + 4 * sg2; cc2 = cc2 < 0 ? 0 : (cc2 > IMW - 4 ? IMW - 4 : cc2);
    const float* gb2 = p2;

    const int wbase = wave * 1024;             // wave-uniform LDS group base

    // ---- fragment read offsets (loop-invariant): row ln, segs s0, s0+1
    const int s0  = 4 * wave + 2 + 2 * lg;
    const int rk0 = (s0 + ln) % 24;
    const int rk1 = (s0 + 1 + ln) % 24;
    const int ro0 = (ln * 24 + rk0) * 16;
    const int ro1 = (ln * 24 + rk1) * 16;
    const int cbase = bx * TX + wave * 16 - 8 + lg * 8;
    const bool colok = ((unsigned)cbase <= (unsigned)(IMW - 8));

    uint2 DA[5], DB[5];
    float lsum = 0.f;

#define CLMP(r) ((r) < 0 ? 0 : ((r) > IMH - 1 ? IMH - 1 : (r)))
#define ISSUE(c, OFF) do{ \
    const int i0 = CLMP(y0 + 16 * (c) - 8 + rw0); \
    const int i1 = CLMP(y0 + 16 * (c) - 8 + rw1); \
    const int i2 = CLMP(y0 + 16 * (c) - 8 + rw2); \
    __builtin_amdgcn_global_load_lds( \
        (const __attribute__((address_space(1))) void*)(gb0 + (size_t)i0 * IMW + cc0), \
        (__attribute__((address_space(3))) void*)(lds + (OFF) + wbase), 16, 0, 0); \
    __builtin_amdgcn_global_load_lds( \
        (const __attribute__((address_space(1))) void*)(gb1 + (size_t)i1 * IMW + cc1), \
        (__attribute__((address_space(3))) void*)(lds + (OFF) + 4096 + wbase), 16, 0, 0); \
    __builtin_amdgcn_global_load_lds( \
        (const __attribute__((address_space(1))) void*)(gb2 + (size_t)i2 * IMW + cc2), \
        (__attribute__((address_space(3))) void*)(lds + (OFF) + 8192 + wbase), 16, 0, 0); \
    } while (0)
#define VMW(n) do{ \
    asm volatile("s_waitcnt vmcnt(" #n ")" ::: "memory"); \
    __builtin_amdgcn_sched_barrier(0); } while (0)
#define BAR() do{ \
    __builtin_amdgcn_sched_barrier(0); \
    __builtin_amdgcn_s_barrier(); \
    __builtin_amdgcn_sched_barrier(0); } while (0)
#define ROWOK(c) (colok && ((unsigned)(y0 + 16 * (c) - 8 + ln) < (unsigned)IMH))

    // ---- prologue: issue chunks 0..2 (9 loads out); wait chunk0; H(0).
    ISSUE(0, 0 * CB);
    ISSUE(1, 1 * CB);
    ISSUE(2, 2 * CB);
    VMW(6);                                // chunk0 writes complete
    BAR();
    cstep<0 * CB>(lds, ro0, ro1, ROWOK(0), whf, sel, DA);   // H of chunk 0

    // ---- main march: step c: ISSUE(c+2 -> buf[(c+2)%4]); vmcnt(6) ->
    // chunk c done, c+1/c+2 in flight across the barrier; cstep(chunk c,
    // buf[c%4]); vstep(tile c-1). Buf reuse separated by step c-1's BAR.
    for (int u = 0; u < 3; ++u) {          // c = 4u+1 .. 4u+4  (1..12)
        const int c0 = 4 * u;
        ISSUE(c0 + 3, 3 * CB); VMW(6); BAR();
        cstep<1 * CB>(lds, ro0, ro1, ROWOK(c0 + 1), whf, sel, DB);
        vstep(whv, DA, DB, lsum);
        ISSUE(c0 + 4, 0 * CB); VMW(6); BAR();
        cstep<2 * CB>(lds, ro0, ro1, ROWOK(c0 + 2), whf, sel, DA);
        vstep(whv, DB, DA, lsum);
        ISSUE(c0 + 5, 1 * CB); VMW(6); BAR();
        cstep<3 * CB>(lds, ro0, ro1, ROWOK(c0 + 3), whf, sel, DB);
        vstep(whv, DA, DB, lsum);
        ISSUE(c0 + 6, 2 * CB); VMW(6); BAR();
        cstep<0 * CB>(lds, ro0, ro1, ROWOK(c0 + 4), whf, sel, DA);
        vstep(whv, DB, DA, lsum);
    }
    // c = 13
    ISSUE(15, 3 * CB); VMW(6); BAR();
    cstep<1 * CB>(lds, ro0, ro1, ROWOK(13), whf, sel, DB);
    vstep(whv, DA, DB, lsum);
    // c = 14
    ISSUE(16, 0 * CB); VMW(6); BAR();
    cstep<2 * CB>(lds, ro0, ro1, ROWOK(14), whf, sel, DA);
    vstep(whv, DB, DA, lsum);
    // c = 15 (no issue; chunk16's 3 loads outstanding)
    VMW(3); BAR();
    cstep<3 * CB>(lds, ro0, ro1, ROWOK(15), whf, sel, DB);
    vstep(whv, DA, DB, lsum);
    // c = 16
    VMW(0); BAR();
    cstep<0 * CB>(lds, ro0, ro1, ROWOK(16), whf, sel, DA);
    vstep(whv, DB, DA, lsum);
#undef CLMP
#undef ISSUE
#undef VMW
#undef BAR
#undef ROWOK

    // ---- Block reduction -> per-block partial ----
#pragma unroll
    for (int off = 32; off > 0; off >>= 1)
        lsum += __shfl_down(lsum, off, 64);

    if (lane == 0) wsum[wave] = lsum;
    __syncthreads();
    if (tid == 0) {
        float tot = wsum[0] + wsum[1] + wsum[2] + wsum[3];
        const int bid = (blockIdx.z * gridDim.y + blockIdx.y) * gridDim.x + blockIdx.x;
        partials[bid] = tot;
    }
}

__global__ __launch_bounds__(256)
void ssim_reduce_kernel(const float* __restrict__ partials,
                        float* __restrict__ out)
{
    __shared__ double sm[256];
    double s = 0.0;
    for (int i = threadIdx.x; i < NBLK; i += 256) s += (double)partials[i];
    sm[threadIdx.x] = s;
    __syncthreads();
    for (int stride = 128; stride > 0; stride >>= 1) {
        if (threadIdx.x < stride) sm[threadIdx.x] += sm[threadIdx.x + stride];
        __syncthreads();
    }
    if (threadIdx.x == 0) {
        double mean = sm[0] / (double)((size_t)NPL * IMW * IMH);
        out[0] = (float)(1.0 - mean);
    }
}

extern "C" void kernel_launch(void* const* d_in, const int* in_sizes, int n_in,
                              void* d_out, int out_size, void* d_ws, size_t ws_size,
                              hipStream_t stream)
{
    (void)in_sizes; (void)n_in; (void)out_size; (void)ws_size;
    const float* img1 = (const float*)d_in[0];
    const float* img2 = (const float*)d_in[1];
    float* out = (float*)d_out;

    unsigned int* wbuf = (unsigned int*)d_ws;              // 2 KB weight table
    float* partials = (float*)((char*)d_ws + 4096);        // NBLK floats

    ssim_weight_setup<<<1, 64, 0, stream>>>(wbuf);
    dim3 grid(GX, GYB, NPL);
    ssim_mfma<<<grid, 256, 0, stream>>>(img1, img2, wbuf, partials);
    ssim_reduce_kernel<<<1, 256, 0, stream>>>(partials, out);
}